// Round 6
// baseline (1758.875 us; speedup 1.0000x reference)
//
#include <hip/hip_runtime.h>
#include <cstdint>
#include <cstddef>

// Problem constants
#define SEQL   256
#define NBATCH 64
#define HDIM   512
#define ZDIM   2048   // 4*OUT
#define KDIM   1536   // in_dim

typedef __attribute__((ext_vector_type(8))) short short8;
typedef __attribute__((ext_vector_type(4))) float f32x4;
typedef __attribute__((ext_vector_type(2))) float f32x2;
typedef __attribute__((ext_vector_type(4))) float f4v;

static __device__ __forceinline__ unsigned short f2bf(float f) {
  union { float f; unsigned u; } v; v.f = f;
  unsigned u = v.u;
  unsigned r = (u + 0x7FFFu + ((u >> 16) & 1u)) >> 16;   // RNE
  return (unsigned short)r;
}
static __device__ __forceinline__ float bf2f(unsigned short s) {
  union { unsigned u; float f; } v; v.u = ((unsigned)s) << 16; return v.f;
}
static __device__ __forceinline__ float sigm(float x)  { return 1.f / (1.f + __expf(-x)); }
static __device__ __forceinline__ float tanh_f(float x){ return 1.f - 2.f / (__expf(2.f * x) + 1.f); }

static __device__ __forceinline__ void gl_lds16(const void* g, void* l) {
  __builtin_amdgcn_global_load_lds((const __attribute__((address_space(1))) unsigned int*)g,
                                   (__attribute__((address_space(3))) unsigned int*)l, 16, 0, 0);
}

// ---------------------------------------------------------------- prep kernels

// x (b,t,k) f32 -> Xb[r][k] bf16 with r = t*64 + b
__global__ __launch_bounds__(256) void k_convx(const float* __restrict__ x,
                                               unsigned short* __restrict__ Xb) {
  int i = blockIdx.x * 256 + threadIdx.x;
  int k8 = (i & 63) * 8;
  int r  = i >> 6;
  int b  = r & 63, t = r >> 6;
  const float* src = x + ((size_t)(b * SEQL + t) * HDIM + k8);
  f4v v0 = *(const f4v*)src;
  f4v v1 = *(const f4v*)(src + 4);
  short8 o;
#pragma unroll
  for (int j = 0; j < 4; ++j) o[j] = (short)f2bf(v0[j]);
#pragma unroll
  for (int j = 0; j < 4; ++j) o[4 + j] = (short)f2bf(v1[j]);
  *(short8*)(Xb + (size_t)r * HDIM + k8) = o;
}

// g (64,512) f32 -> bf16
__global__ __launch_bounds__(256) void k_convg(const float* __restrict__ g,
                                               unsigned short* __restrict__ gbf) {
  int i = blockIdx.x * 256 + threadIdx.x;
  int k8 = (i & 63) * 8;
  int row = i >> 6;
  const float* src = g + ((size_t)row * HDIM + k8);
  f4v v0 = *(const f4v*)src;
  f4v v1 = *(const f4v*)(src + 4);
  short8 o;
#pragma unroll
  for (int j = 0; j < 4; ++j) o[j] = (short)f2bf(v0[j]);
#pragma unroll
  for (int j = 0; j < 4; ++j) o[4 + j] = (short)f2bf(v1[j]);
  *(short8*)(gbf + (size_t)row * HDIM + k8) = o;
}

// W (1536,2048) f32 -> Wt (2048,1536) bf16 (transposed)
__global__ __launch_bounds__(256) void k_trans(const float* __restrict__ W,
                                               unsigned short* __restrict__ Wt) {
  __shared__ float tile[32][33];
  int tx = threadIdx.x & 31, ty = threadIdx.x >> 5;
  int n0 = blockIdx.x * 32;
  int j0 = blockIdx.y * 32;
#pragma unroll
  for (int jj = 0; jj < 4; ++jj)
    tile[ty + jj * 8][tx] = W[(size_t)(j0 + ty + jj * 8) * ZDIM + n0 + tx];
  __syncthreads();
#pragma unroll
  for (int jj = 0; jj < 4; ++jj)
    Wt[(size_t)(n0 + ty + jj * 8) * KDIM + j0 + tx] = f2bf(tile[tx][ty + jj * 8]);
}

// gbuf[64][2048] = g @ Wg + bias
__global__ __launch_bounds__(256) void k_gb(const unsigned short* __restrict__ gbf,
                                            const unsigned short* __restrict__ Wt,
                                            const float* __restrict__ bias,
                                            float* __restrict__ gbuf) {
  int tid = threadIdx.x, l = tid & 63, w = tid >> 6;
  int n0 = blockIdx.x * 64 + w * 16;
  f32x4 acc[4] = {};
#pragma unroll
  for (int kb = 0; kb < 16; ++kb) {
    short8 bfr = *(const short8*)((const char*)Wt + (size_t)(n0 + (l & 15)) * 3072
                                  + 2048 + kb * 64 + (l >> 4) * 16);
#pragma unroll
    for (int mi = 0; mi < 4; ++mi) {
      short8 afr = *(const short8*)((const char*)gbf + (size_t)(mi * 16 + (l & 15)) * 1024
                                    + kb * 64 + (l >> 4) * 16);
      acc[mi] = __builtin_amdgcn_mfma_f32_16x16x32_bf16(afr, bfr, acc[mi], 0, 0, 0);
    }
  }
  int r0 = (l >> 4) * 4, cq = l & 15;
#pragma unroll
  for (int mi = 0; mi < 4; ++mi)
#pragma unroll
    for (int reg = 0; reg < 4; ++reg) {
      int row = mi * 16 + r0 + reg, col = n0 + cq;
      gbuf[(size_t)row * ZDIM + col] = acc[mi][reg] + bias[col];
    }
}

// ------------------------------------------------- phase-1 GEMM: zpre = Xb @ Wx^T + gbuf
__global__ __launch_bounds__(256, 2) void k_gemm_p1(const unsigned short* __restrict__ Xb,
                                                    const unsigned short* __restrict__ Wt,
                                                    const float* __restrict__ gbuf,
                                                    unsigned short* __restrict__ zpre) {
  __shared__ unsigned char sm[32768];
  int tm = blockIdx.x, tn = blockIdx.y;
  int tid = threadIdx.x, l = tid & 63, w = tid >> 6;
  int m0w = (w & 1) * 64, n0w = (w >> 1) * 64;
  f32x4 acc[4][4] = {};

  for (int k0 = 0; k0 < HDIM; k0 += 64) {
#pragma unroll
    for (int j = 0; j < 8; ++j) {
      int c = j * 4 + w;
      int lane_row = l >> 3;
      int kb = (l & 7) * 16;
      const char* gsrc;
      if (c < 16) {
        int row = c * 8 + lane_row;
        gsrc = (const char*)Xb + (size_t)(tm * 128 + row) * 1024 + k0 * 2 + kb;
      } else {
        int row = (c - 16) * 8 + lane_row;
        gsrc = (const char*)Wt + (size_t)(tn * 128 + row) * 3072 + k0 * 2 + kb;
      }
      gl_lds16(gsrc, (char*)sm + c * 1024);
    }
    __syncthreads();

#pragma unroll
    for (int kk = 0; kk < 64; kk += 32) {
      short8 af[4], bf[4];
#pragma unroll
      for (int mi = 0; mi < 4; ++mi)
        af[mi] = *(const short8*)((const char*)sm + (size_t)(m0w + mi * 16 + (l & 15)) * 128
                                  + (kk + (l >> 4) * 8) * 2);
#pragma unroll
      for (int ni = 0; ni < 4; ++ni)
        bf[ni] = *(const short8*)((const char*)sm + 16384 + (size_t)(n0w + ni * 16 + (l & 15)) * 128
                                  + (kk + (l >> 4) * 8) * 2);
#pragma unroll
      for (int mi = 0; mi < 4; ++mi)
#pragma unroll
        for (int ni = 0; ni < 4; ++ni)
          acc[mi][ni] = __builtin_amdgcn_mfma_f32_16x16x32_bf16(af[mi], bf[ni], acc[mi][ni], 0, 0, 0);
    }
    __syncthreads();
  }

  int r0 = (l >> 4) * 4, cq = l & 15;
#pragma unroll
  for (int mi = 0; mi < 4; ++mi)
#pragma unroll
    for (int ni = 0; ni < 4; ++ni) {
      int col = tn * 128 + n0w + ni * 16 + cq;
#pragma unroll
      for (int reg = 0; reg < 4; ++reg) {
        int row = tm * 128 + m0w + mi * 16 + r0 + reg;
        float v = acc[mi][ni][reg] + gbuf[(size_t)(row & 63) * ZDIM + col];
        zpre[(size_t)row * ZDIM + col] = f2bf(v);
      }
    }
}

// ---------------------------------------------------------- persistent recurrence
// 128 wgs = dir(2) x band(4; 16 rows) x colgroup(16; 32 h-cols). 4 waves = 4 gates.
// 8 sync groups (dir,band) of 16 wgs, flag-broadcast through L2-bypassing
// (system-scope relaxed) atomics. Critical path is ONE wave: after the zbuf
// handoff barrier, wave 0 does all gate math, stores h (16B/lane, bypass),
// wave-local s_waitcnt vmcnt(0), publishes the flag. Waves 1-3 immediately
// return to polling. One __syncthreads() per step.

__global__ __launch_bounds__(256, 1) void k_rec(const unsigned short* __restrict__ Wt,
                                                const unsigned short* __restrict__ zpre,
                                                unsigned short* __restrict__ hbuf, // [2][2][4][16][512] bf16
                                                unsigned* __restrict__ sync_ws,
                                                float* __restrict__ out,
                                                float* __restrict__ hstate,
                                                float* __restrict__ cstate) {
  __shared__ short lwh[4 * 32 * 512];     // 128KB: [gate][col(32)][k(512)] bf16, XOR-swizzled
  __shared__ float zbuf[2][4][16][33];    // ~16.9KB, +1 pad col (bank-conflict-free gate math)

  const int tid = threadIdx.x, l = tid & 63, gi = tid >> 6;   // wave = gate (i,f,o,u)
  const int bid = blockIdx.x;
  const int cg = bid & 15, gid = bid >> 4, dir = gid >> 2, bg = gid & 3;
  const int hc0 = cg * 32;

  // stage Wh slice (gate gi, cols hc0..hc0+31) into LDS; each wave stages and
  // consumes only its own gate's region -> no barrier needed.
#pragma unroll
  for (int col = 0; col < 32; ++col) {
    int kbs = l * 16;
    int kbyte = kbs ^ ((col & 7) << 4);
    short8 v = *(const short8*)((const char*)Wt
                + (size_t)(gi * 512 + hc0 + col) * 3072 + 1024 + kbyte);
    *(short8*)((char*)lwh + gi * 32768 + col * 1024 + kbs) = v;
  }

  unsigned* fl = sync_ws + gid * 256;   // 16 flags x 64B for this (dir,band) group

  // wave-0 gate-math coords: lane l -> row (l&15), col-block (l>>4) of 8 cols
  const int rw = l & 15, cb = l >> 4;
  float c_[8] = {0.f, 0.f, 0.f, 0.f, 0.f, 0.f, 0.f, 0.f};
  float h_[8] = {0.f, 0.f, 0.f, 0.f, 0.f, 0.f, 0.f, 0.f};

  // zpre prefetch for first step (wave 0 only; 4 gates x 8 cols bf16)
  short8 zp4[4];
  if (gi == 0) {
    int t0 = dir ? (SEQL - 1) : 0;
    const unsigned short* zb = zpre + ((size_t)t0 * 64 + bg * 16 + rw) * ZDIM + hc0 + cb * 8;
#pragma unroll
    for (int gg = 0; gg < 4; ++gg) zp4[gg] = *(const short8*)(zb + gg * 512);
  }

  // A-fragment per-lane byte offset (16x16x32: row=l&15, k-chunk by l>>4)
  const int a_off = (l & 15) * 1024 + (l >> 4) * 16;

  for (int s = 0; s < SEQL; ++s) {
    int t = dir ? (SEQL - 1 - s) : s;
    int rb = s & 1, wb = rb ^ 1;
    f32x4 acc0 = {0.f, 0.f, 0.f, 0.f}, acc1 = {0.f, 0.f, 0.f, 0.f};

    if (s) {
      // every wave polls independently: lanes 0-15 watch the 16 group flags
      if (l < 16) {
        long gd = 0;
        while (__hip_atomic_load(fl + l * 16, __ATOMIC_RELAXED,
                                 __HIP_MEMORY_SCOPE_SYSTEM) < (unsigned)s) {
          __builtin_amdgcn_s_sleep(1);
          if (++gd > (1L << 22)) break;   // hang guard
        }
      }
      // wave reconvergence here orders the A-loads after poll success

      const char* ha = (const char*)hbuf
          + (((size_t)(rb * 2 + dir)) * 4 + bg) * 16384 + a_off;
      short8 afr[16];
#pragma unroll
      for (int kb = 0; kb < 16; ++kb) {
        union { unsigned long long u[2]; short8 s8; } cv;
        cv.u[0] = __hip_atomic_load((const unsigned long long*)(ha + kb * 64),
                                    __ATOMIC_RELAXED, __HIP_MEMORY_SCOPE_SYSTEM);
        cv.u[1] = __hip_atomic_load((const unsigned long long*)(ha + kb * 64 + 8),
                                    __ATOMIC_RELAXED, __HIP_MEMORY_SCOPE_SYSTEM);
        afr[kb] = cv.s8;
      }

#pragma unroll
      for (int kb = 0; kb < 16; ++kb) {
        int kfrag = kb * 64 + (l >> 4) * 16;
        int kbyte = kfrag ^ ((l & 7) << 4);
        short8 b0 = *(const short8*)((const char*)lwh + gi * 32768 + (size_t)(l & 15) * 1024 + kbyte);
        short8 b1 = *(const short8*)((const char*)lwh + gi * 32768 + (size_t)(16 + (l & 15)) * 1024 + kbyte);
        acc0 = __builtin_amdgcn_mfma_f32_16x16x32_bf16(afr[kb], b0, acc0, 0, 0, 0);
        acc1 = __builtin_amdgcn_mfma_f32_16x16x32_bf16(afr[kb], b1, acc1, 0, 0, 0);
      }
    }
    // s==0: h=0 => Wh contribution zero; accs stay 0.

    {
      int col = l & 15, row0 = (l >> 4) * 4;
#pragma unroll
      for (int reg = 0; reg < 4; ++reg) {
        zbuf[rb][gi][row0 + reg][col]      = acc0[reg];
        zbuf[rb][gi][row0 + reg][col + 16] = acc1[reg];
      }
    }
    __syncthreads();   // the ONLY block barrier per step (zbuf handoff)

    if (gi == 0) {
      // gate math for the whole 16x32 slice: lane (rw, cb) owns cols cb*8..cb*8+7
      short8 hp;
#pragma unroll
      for (int j = 0; j < 8; ++j) {
        int col = cb * 8 + j;
        float zi = zbuf[rb][0][rw][col] + bf2f((unsigned short)zp4[0][j]);
        float zf = zbuf[rb][1][rw][col] + bf2f((unsigned short)zp4[1][j]);
        float zo = zbuf[rb][2][rw][col] + bf2f((unsigned short)zp4[2][j]);
        float zu = zbuf[rb][3][rw][col] + bf2f((unsigned short)zp4[3][j]);
        c_[j] = sigm(zf) * c_[j] + sigm(zi) * tanh_f(zu);
        h_[j] = sigm(zo) * tanh_f(c_[j]);
        hp[j] = (short)f2bf(h_[j]);
      }

      // publish h: one 16B (2x8B bypass) store per lane
      char* hdst = (char*)hbuf + (((size_t)(wb * 2 + dir)) * 4 + bg) * 16384
                   + rw * 1024 + (hc0 + cb * 8) * 2;
      union { unsigned long long u[2]; short8 s8; } pk;
      pk.s8 = hp;
      __hip_atomic_store((unsigned long long*)hdst, pk.u[0],
                         __ATOMIC_RELAXED, __HIP_MEMORY_SCOPE_SYSTEM);
      __hip_atomic_store((unsigned long long*)(hdst + 8), pk.u[1],
                         __ATOMIC_RELAXED, __HIP_MEMORY_SCOPE_SYSTEM);
      asm volatile("s_waitcnt vmcnt(0)" ::: "memory");   // wave-local drain
      if (l == 0)
        __hip_atomic_store(fl + cg * 16, (unsigned)(s + 1),
                           __ATOMIC_RELAXED, __HIP_MEMORY_SCOPE_SYSTEM);

      // off-critical-path: out stores (8 f32/lane, nontemporal)
      {
        float* ob = out + ((size_t)(bg * 16 + rw) * SEQL + t) * 1024 + dir * 512 + hc0 + cb * 8;
        f32x4 v0 = {h_[0], h_[1], h_[2], h_[3]};
        f32x4 v1 = {h_[4], h_[5], h_[6], h_[7]};
        __builtin_nontemporal_store(v0, (f32x4*)ob);
        __builtin_nontemporal_store(v1, (f32x4*)(ob + 4));
      }

      // prefetch next step's zpre (overlaps next poll)
      if (s + 1 < SEQL) {
        int tn = dir ? (SEQL - 2 - s) : (s + 1);
        const unsigned short* zb = zpre + ((size_t)tn * 64 + bg * 16 + rw) * ZDIM + hc0 + cb * 8;
#pragma unroll
        for (int gg = 0; gg < 4; ++gg) zp4[gg] = *(const short8*)(zb + gg * 512);
      }
    }
    // waves 1-3 loop straight back to the poll
  }

  // final states (wave 0 holds them)
  if (gi == 0) {
    float* hb = hstate + (size_t)(bg * 16 + rw) * 1024 + dir * 512 + hc0 + cb * 8;
    float* cb2 = cstate + (size_t)(bg * 16 + rw) * 1024 + dir * 512 + hc0 + cb * 8;
    f32x4 hv0 = {h_[0], h_[1], h_[2], h_[3]};
    f32x4 hv1 = {h_[4], h_[5], h_[6], h_[7]};
    f32x4 cv0 = {c_[0], c_[1], c_[2], c_[3]};
    f32x4 cv1 = {c_[4], c_[5], c_[6], c_[7]};
    __builtin_nontemporal_store(hv0, (f32x4*)hb);
    __builtin_nontemporal_store(hv1, (f32x4*)(hb + 4));
    __builtin_nontemporal_store(cv0, (f32x4*)cb2);
    __builtin_nontemporal_store(cv1, (f32x4*)(cb2 + 4));
  }
}

// ---------------------------------------------------------------------- launch

extern "C" void kernel_launch(void* const* d_in, const int* in_sizes, int n_in,
                              void* d_out, int out_size, void* d_ws, size_t ws_size,
                              hipStream_t stream) {
  const float* x    = (const float*)d_in[0];
  const float* g    = (const float*)d_in[1];
  const float* W    = (const float*)d_in[2];
  const float* bias = (const float*)d_in[3];
  float* out = (float*)d_out;
  float* hstate = out + (size_t)16777216;            // 64*256*1024
  float* cstate = out + (size_t)16842752;            // + 64*1024

  char* ws = (char*)d_ws;
  unsigned*       sync_ws = (unsigned*)(ws + 0);              // 8KB: 8 groups x 16 flags x 64B
  unsigned short* hbuf = (unsigned short*)(ws + 8192);        // 256KB [2][2][4][16][512]
  unsigned short* Xb   = (unsigned short*)(ws + 270336);      // 16MB
  unsigned short* Wt   = (unsigned short*)(ws + 17047552);    // 6MB
  unsigned short* gbf  = (unsigned short*)(ws + 23339008);    // 64KB
  float*          gbuf = (float*)(ws + 23404544);             // 512KB
  unsigned short* zpre = (unsigned short*)(ws + 23928832);    // 64MB

  hipMemsetAsync((void*)sync_ws, 0, 8192, stream);

  k_convx<<<4096, 256, 0, stream>>>(x, Xb);
  k_convg<<<16, 256, 0, stream>>>(g, gbf);
  k_trans<<<dim3(64, 48), 256, 0, stream>>>(W, Wt);
  k_gb<<<32, 256, 0, stream>>>(gbf, Wt, bias, gbuf);
  k_gemm_p1<<<dim3(128, 16), 256, 0, stream>>>(Xb, Wt, gbuf, zpre);
  k_rec<<<128, 256, 0, stream>>>(Wt, zpre, hbuf, sync_ws, out, hstate, cstate);
}

// Round 8
// 781.263 us; speedup vs baseline: 2.2513x; 2.2513x over previous
//
#include <hip/hip_runtime.h>
#include <cstdint>
#include <cstddef>

// Problem constants
#define SEQL   256
#define NBATCH 64
#define HDIM   512
#define ZDIM   2048   // 4*OUT
#define KDIM   1536   // in_dim

typedef __attribute__((ext_vector_type(8))) short short8;
typedef __attribute__((ext_vector_type(4))) float f32x4;
typedef __attribute__((ext_vector_type(2))) float f32x2;
typedef __attribute__((ext_vector_type(4))) float f4v;

static __device__ __forceinline__ unsigned short f2bf(float f) {
  union { float f; unsigned u; } v; v.f = f;
  unsigned u = v.u;
  unsigned r = (u + 0x7FFFu + ((u >> 16) & 1u)) >> 16;   // RNE
  return (unsigned short)r;
}
static __device__ __forceinline__ float bf2f(unsigned short s) {
  union { unsigned u; float f; } v; v.u = ((unsigned)s) << 16; return v.f;
}
static __device__ __forceinline__ float sigm(float x)  { return 1.f / (1.f + __expf(-x)); }
static __device__ __forceinline__ float tanh_f(float x){ return 1.f - 2.f / (__expf(2.f * x) + 1.f); }

static __device__ __forceinline__ void gl_lds16(const void* g, void* l) {
  __builtin_amdgcn_global_load_lds((const __attribute__((address_space(1))) unsigned int*)g,
                                   (__attribute__((address_space(3))) unsigned int*)l, 16, 0, 0);
}

// ---------------------------------------------------------------- prep kernels

// x (b,t,k) f32 -> Xb[r][k] bf16 with r = t*64 + b
__global__ __launch_bounds__(256) void k_convx(const float* __restrict__ x,
                                               unsigned short* __restrict__ Xb) {
  int i = blockIdx.x * 256 + threadIdx.x;
  int k8 = (i & 63) * 8;
  int r  = i >> 6;
  int b  = r & 63, t = r >> 6;
  const float* src = x + ((size_t)(b * SEQL + t) * HDIM + k8);
  f4v v0 = *(const f4v*)src;
  f4v v1 = *(const f4v*)(src + 4);
  short8 o;
#pragma unroll
  for (int j = 0; j < 4; ++j) o[j] = (short)f2bf(v0[j]);
#pragma unroll
  for (int j = 0; j < 4; ++j) o[4 + j] = (short)f2bf(v1[j]);
  *(short8*)(Xb + (size_t)r * HDIM + k8) = o;
}

// g (64,512) f32 -> bf16
__global__ __launch_bounds__(256) void k_convg(const float* __restrict__ g,
                                               unsigned short* __restrict__ gbf) {
  int i = blockIdx.x * 256 + threadIdx.x;
  int k8 = (i & 63) * 8;
  int row = i >> 6;
  const float* src = g + ((size_t)row * HDIM + k8);
  f4v v0 = *(const f4v*)src;
  f4v v1 = *(const f4v*)(src + 4);
  short8 o;
#pragma unroll
  for (int j = 0; j < 4; ++j) o[j] = (short)f2bf(v0[j]);
#pragma unroll
  for (int j = 0; j < 4; ++j) o[4 + j] = (short)f2bf(v1[j]);
  *(short8*)(gbf + (size_t)row * HDIM + k8) = o;
}

// W (1536,2048) f32 -> Wt (2048,1536) bf16 (transposed)
__global__ __launch_bounds__(256) void k_trans(const float* __restrict__ W,
                                               unsigned short* __restrict__ Wt) {
  __shared__ float tile[32][33];
  int tx = threadIdx.x & 31, ty = threadIdx.x >> 5;
  int n0 = blockIdx.x * 32;
  int j0 = blockIdx.y * 32;
#pragma unroll
  for (int jj = 0; jj < 4; ++jj)
    tile[ty + jj * 8][tx] = W[(size_t)(j0 + ty + jj * 8) * ZDIM + n0 + tx];
  __syncthreads();
#pragma unroll
  for (int jj = 0; jj < 4; ++jj)
    Wt[(size_t)(n0 + ty + jj * 8) * KDIM + j0 + tx] = f2bf(tile[tx][ty + jj * 8]);
}

// gbuf[64][2048] = g @ Wg + bias
__global__ __launch_bounds__(256) void k_gb(const unsigned short* __restrict__ gbf,
                                            const unsigned short* __restrict__ Wt,
                                            const float* __restrict__ bias,
                                            float* __restrict__ gbuf) {
  int tid = threadIdx.x, l = tid & 63, w = tid >> 6;
  int n0 = blockIdx.x * 64 + w * 16;
  f32x4 acc[4] = {};
#pragma unroll
  for (int kb = 0; kb < 16; ++kb) {
    short8 bfr = *(const short8*)((const char*)Wt + (size_t)(n0 + (l & 15)) * 3072
                                  + 2048 + kb * 64 + (l >> 4) * 16);
#pragma unroll
    for (int mi = 0; mi < 4; ++mi) {
      short8 afr = *(const short8*)((const char*)gbf + (size_t)(mi * 16 + (l & 15)) * 1024
                                    + kb * 64 + (l >> 4) * 16);
      acc[mi] = __builtin_amdgcn_mfma_f32_16x16x32_bf16(afr, bfr, acc[mi], 0, 0, 0);
    }
  }
  int r0 = (l >> 4) * 4, cq = l & 15;
#pragma unroll
  for (int mi = 0; mi < 4; ++mi)
#pragma unroll
    for (int reg = 0; reg < 4; ++reg) {
      int row = mi * 16 + r0 + reg, col = n0 + cq;
      gbuf[(size_t)row * ZDIM + col] = acc[mi][reg] + bias[col];
    }
}

// ------------------------------------------------- phase-1 GEMM: zpre = Xb @ Wx^T + gbuf
__global__ __launch_bounds__(256, 2) void k_gemm_p1(const unsigned short* __restrict__ Xb,
                                                    const unsigned short* __restrict__ Wt,
                                                    const float* __restrict__ gbuf,
                                                    unsigned short* __restrict__ zpre) {
  __shared__ unsigned char sm[32768];
  int tm = blockIdx.x, tn = blockIdx.y;
  int tid = threadIdx.x, l = tid & 63, w = tid >> 6;
  int m0w = (w & 1) * 64, n0w = (w >> 1) * 64;
  f32x4 acc[4][4] = {};

  for (int k0 = 0; k0 < HDIM; k0 += 64) {
#pragma unroll
    for (int j = 0; j < 8; ++j) {
      int c = j * 4 + w;
      int lane_row = l >> 3;
      int kb = (l & 7) * 16;
      const char* gsrc;
      if (c < 16) {
        int row = c * 8 + lane_row;
        gsrc = (const char*)Xb + (size_t)(tm * 128 + row) * 1024 + k0 * 2 + kb;
      } else {
        int row = (c - 16) * 8 + lane_row;
        gsrc = (const char*)Wt + (size_t)(tn * 128 + row) * 3072 + k0 * 2 + kb;
      }
      gl_lds16(gsrc, (char*)sm + c * 1024);
    }
    __syncthreads();

#pragma unroll
    for (int kk = 0; kk < 64; kk += 32) {
      short8 af[4], bf[4];
#pragma unroll
      for (int mi = 0; mi < 4; ++mi)
        af[mi] = *(const short8*)((const char*)sm + (size_t)(m0w + mi * 16 + (l & 15)) * 128
                                  + (kk + (l >> 4) * 8) * 2);
#pragma unroll
      for (int ni = 0; ni < 4; ++ni)
        bf[ni] = *(const short8*)((const char*)sm + 16384 + (size_t)(n0w + ni * 16 + (l & 15)) * 128
                                  + (kk + (l >> 4) * 8) * 2);
#pragma unroll
      for (int mi = 0; mi < 4; ++mi)
#pragma unroll
        for (int ni = 0; ni < 4; ++ni)
          acc[mi][ni] = __builtin_amdgcn_mfma_f32_16x16x32_bf16(af[mi], bf[ni], acc[mi][ni], 0, 0, 0);
    }
    __syncthreads();
  }

  int r0 = (l >> 4) * 4, cq = l & 15;
#pragma unroll
  for (int mi = 0; mi < 4; ++mi)
#pragma unroll
    for (int ni = 0; ni < 4; ++ni) {
      int col = tn * 128 + n0w + ni * 16 + cq;
#pragma unroll
      for (int reg = 0; reg < 4; ++reg) {
        int row = tm * 128 + m0w + mi * 16 + r0 + reg;
        float v = acc[mi][ni][reg] + gbuf[(size_t)(row & 63) * ZDIM + col];
        zpre[(size_t)row * ZDIM + col] = f2bf(v);
      }
    }
}

// ---------------------------------------------------------- persistent recurrence
// 128 wgs = dir(2) x band(4; 16 rows) x colgroup(16; 32 h-cols). 4 waves = 4 gates.
// SYNC: each h col-pair is an 8B atomic packet {u32 data = 2xbf16 exact, u32
// stamp = step}. Producers fire one 8B relaxed SYSTEM (L2-bypassing) store --
// no drain, no flag, no fence. Consumers retry 8B loads until stamp == s-1:
// detect + fetch = ONE IF round trip, exact payload. Two regions by s&1;
// overwrite-safety by data dependency (a wg writes h(s+1) only after its
// step-s A-loads of h(s-1) returned). Waves cooperatively stage A into LDS
// (each wave polls its own 4 k-chunks) -> 4x less L3 traffic than per-wave
// redundant loads. Regions pre-stamped 0xFF each launch.

__global__ __launch_bounds__(256, 1) void k_rec(const unsigned short* __restrict__ Wt,
                                                const unsigned short* __restrict__ zpre,
                                                unsigned long long* __restrict__ hbuf8, // [2][2][64][256] packets
                                                float* __restrict__ out,
                                                float* __restrict__ hstate,
                                                float* __restrict__ cstate) {
  __shared__ short lwh[4 * 32 * 512];         // 128KB: [gate][col(32)][k(512)] bf16, XOR-swizzled
  __shared__ unsigned char As[16 * 1024];     // 16KB: A tile [row(16)][k(512)] bf16, XOR-swizzled
  __shared__ float zbuf[4][16][33];           // 8.4KB (+1 pad col)

  const int tid = threadIdx.x, l = tid & 63, gi = tid >> 6;   // wave = gate (i,f,o,u)
  const int bid = blockIdx.x;
  const int cg = bid & 15, gid = bid >> 4, dir = gid >> 2, bg = gid & 3;
  const int hc0 = cg * 32;

  // stage Wh slice (gate gi, cols hc0..hc0+31) into LDS; per-wave private region.
#pragma unroll
  for (int col = 0; col < 32; ++col) {
    int kbs = l * 16;
    int kbyte = kbs ^ ((col & 7) << 4);
    short8 v = *(const short8*)((const char*)Wt
                + (size_t)(gi * 512 + hc0 + col) * 3072 + 1024 + kbyte);
    *(short8*)((char*)lwh + gi * 32768 + col * 1024 + kbs) = v;
  }

  const int r = tid >> 4, q = tid & 15;   // gate-math: row r (0..15), cols 2q, 2q+1
  float c0 = 0.f, c1 = 0.f, h0 = 0.f, h1 = 0.f;

  // prefetch zpre for first step (cached loads; L2 stays warm)
  int t = dir ? (SEQL - 1) : 0;
  unsigned zp[4];
  {
    const char* zb = (const char*)zpre
        + (((size_t)t * 64 + bg * 16 + r) * ZDIM + hc0 + 2 * q) * 2;
#pragma unroll
    for (int gg = 0; gg < 4; ++gg) zp[gg] = *(const unsigned*)(zb + gg * 1024);
  }

  // producer packet index: [dir*64 + bg*16 + r][cg*16 + q]
  const size_t p_idx = ((size_t)(dir * 64 + bg * 16 + r)) * 256 + cg * 16 + q;
  // consumer: wave gi polls k-chunks kb = gi*4..gi*4+3; lane handles
  // rows it*4 + (l>>4), col-pair (l&15) of each chunk.
  const int c_row = l >> 4, c_cp = l & 15;

  for (int s = 0; s < SEQL; ++s) {
    f32x4 acc0 = {0.f, 0.f, 0.f, 0.f}, acc1 = {0.f, 0.f, 0.f, 0.f};

    if (s) {
      // ---- poll + load A packets (this wave's 4 k-chunks), strip to LDS
      const unsigned expect = (unsigned)(s - 1);
      const unsigned long long* hb = hbuf8 + (size_t)((s - 1) & 1) * 32768;
      unsigned long long v[16];
      int gd = 0;
      bool ok;
      do {
#pragma unroll
        for (int it = 0; it < 4; ++it)
#pragma unroll
          for (int kk = 0; kk < 4; ++kk) {
            int row = it * 4 + c_row;
            int kb = gi * 4 + kk;
            v[it * 4 + kk] = __hip_atomic_load(
                hb + ((size_t)(dir * 64 + bg * 16 + row)) * 256 + kb * 16 + c_cp,
                __ATOMIC_RELAXED, __HIP_MEMORY_SCOPE_SYSTEM);
          }
        ok = true;
#pragma unroll
        for (int i = 0; i < 16; ++i) ok = ok && ((unsigned)(v[i] >> 32) == expect);
      } while (!__all(ok) && ++gd < (1 << 16));   // hang guard

#pragma unroll
      for (int it = 0; it < 4; ++it)
#pragma unroll
        for (int kk = 0; kk < 4; ++kk) {
          int row = it * 4 + c_row;
          int kb = gi * 4 + kk;
          int byte = (row * 1024 + kb * 64 + c_cp * 4) ^ ((row & 7) << 4);
          *(unsigned*)(As + byte) = (unsigned)v[it * 4 + kk];
        }
    }
    __syncthreads();   // A tile ready in LDS (or s==0: nothing, acc stays 0)

    if (s) {
#pragma unroll
      for (int kb = 0; kb < 16; ++kb) {
        int arow = l & 15;
        int abyte = (arow * 1024 + kb * 64 + (l >> 4) * 16) ^ ((arow & 7) << 4);
        short8 a = *(const short8*)(As + abyte);
        int kfrag = kb * 64 + (l >> 4) * 16;
        int kbyte = kfrag ^ ((l & 7) << 4);
        short8 b0 = *(const short8*)((const char*)lwh + gi * 32768 + (size_t)(l & 15) * 1024 + kbyte);
        short8 b1 = *(const short8*)((const char*)lwh + gi * 32768 + (size_t)(16 + (l & 15)) * 1024 + kbyte);
        acc0 = __builtin_amdgcn_mfma_f32_16x16x32_bf16(a, b0, acc0, 0, 0, 0);
        acc1 = __builtin_amdgcn_mfma_f32_16x16x32_bf16(a, b1, acc1, 0, 0, 0);
      }
    }

    {
      int col = l & 15, row0 = (l >> 4) * 4;
#pragma unroll
      for (int reg = 0; reg < 4; ++reg) {
        zbuf[gi][row0 + reg][col]      = acc0[reg];
        zbuf[gi][row0 + reg][col + 16] = acc1[reg];
      }
    }
    __syncthreads();   // zbuf handoff

    // gate math: thread owns (row r, cols 2q, 2q+1)
    float zi0 = zbuf[0][r][2 * q]     + bf2f((unsigned short)(zp[0] & 0xffffu));
    float zi1 = zbuf[0][r][2 * q + 1] + bf2f((unsigned short)(zp[0] >> 16));
    float zf0 = zbuf[1][r][2 * q]     + bf2f((unsigned short)(zp[1] & 0xffffu));
    float zf1 = zbuf[1][r][2 * q + 1] + bf2f((unsigned short)(zp[1] >> 16));
    float zo0 = zbuf[2][r][2 * q]     + bf2f((unsigned short)(zp[2] & 0xffffu));
    float zo1 = zbuf[2][r][2 * q + 1] + bf2f((unsigned short)(zp[2] >> 16));
    float zu0 = zbuf[3][r][2 * q]     + bf2f((unsigned short)(zp[3] & 0xffffu));
    float zu1 = zbuf[3][r][2 * q + 1] + bf2f((unsigned short)(zp[3] >> 16));

    c0 = sigm(zf0) * c0 + sigm(zi0) * tanh_f(zu0);
    h0 = sigm(zo0) * tanh_f(c0);
    c1 = sigm(zf1) * c1 + sigm(zi1) * tanh_f(zu1);
    h1 = sigm(zo1) * tanh_f(c1);

    // publish h packet: {2xbf16 exact, stamp = s} one 8B atomic store
    {
      unsigned hd = (unsigned)f2bf(h0) | ((unsigned)f2bf(h1) << 16);
      unsigned long long pv = (unsigned long long)hd
                            | ((unsigned long long)(unsigned)s << 32);
      __hip_atomic_store(hbuf8 + (size_t)(s & 1) * 32768 + p_idx, pv,
                         __ATOMIC_RELAXED, __HIP_MEMORY_SCOPE_SYSTEM);
    }

    // off-critical-path: out store + next zpre prefetch
    {
      f32x2 ho; ho.x = h0; ho.y = h1;
      __builtin_nontemporal_store(ho, reinterpret_cast<f32x2*>(
          out + ((size_t)(bg * 16 + r) * SEQL + t) * 1024 + dir * 512 + hc0 + 2 * q));
    }
    if (s + 1 < SEQL) {
      t = dir ? (SEQL - 2 - s) : (s + 1);
      const char* zb = (const char*)zpre
          + (((size_t)t * 64 + bg * 16 + r) * ZDIM + hc0 + 2 * q) * 2;
#pragma unroll
      for (int gg = 0; gg < 4; ++gg) zp[gg] = *(const unsigned*)(zb + gg * 1024);
    }
  }

  // final states
  {
    size_t st = (size_t)(bg * 16 + r) * 1024 + dir * 512 + hc0 + 2 * q;
    f32x2 hv; hv.x = h0; hv.y = h1;
    f32x2 cv2; cv2.x = c0; cv2.y = c1;
    __builtin_nontemporal_store(hv, reinterpret_cast<f32x2*>(hstate + st));
    __builtin_nontemporal_store(cv2, reinterpret_cast<f32x2*>(cstate + st));
  }
}

// ---------------------------------------------------------------------- launch

extern "C" void kernel_launch(void* const* d_in, const int* in_sizes, int n_in,
                              void* d_out, int out_size, void* d_ws, size_t ws_size,
                              hipStream_t stream) {
  const float* x    = (const float*)d_in[0];
  const float* g    = (const float*)d_in[1];
  const float* W    = (const float*)d_in[2];
  const float* bias = (const float*)d_in[3];
  float* out = (float*)d_out;
  float* hstate = out + (size_t)16777216;            // 64*256*1024
  float* cstate = out + (size_t)16842752;            // + 64*1024

  char* ws = (char*)d_ws;
  unsigned long long* hbuf8 = (unsigned long long*)(ws + 0);  // 512KB: 2 regions x [2][64][256] x 8B
  unsigned short* Xb   = (unsigned short*)(ws + 524288);      // 16MB
  unsigned short* Wt   = (unsigned short*)(ws + 17301504);    // 6MB
  unsigned short* gbf  = (unsigned short*)(ws + 23592960);    // 64KB
  float*          gbuf = (float*)(ws + 23658496);             // 512KB
  unsigned short* zpre = (unsigned short*)(ws + 24182784);    // 64MB

  // pre-stamp both h regions with 0xFFFFFFFF stamps (matches no expected step;
  // also cleans previous replay's stamps -- harness doesn't re-poison ws).
  hipMemsetAsync((void*)hbuf8, 0xFF, 524288, stream);

  k_convx<<<4096, 256, 0, stream>>>(x, Xb);
  k_convg<<<16, 256, 0, stream>>>(g, gbf);
  k_trans<<<dim3(64, 48), 256, 0, stream>>>(W, Wt);
  k_gb<<<32, 256, 0, stream>>>(gbf, Wt, bias, gbuf);
  k_gemm_p1<<<dim3(128, 16), 256, 0, stream>>>(Xb, Wt, gbuf, zpre);
  k_rec<<<128, 256, 0, stream>>>(Wt, zpre, hbuf8, out, hstate, cstate);
}